// Round 6
// baseline (147.602 us; speedup 1.0000x reference)
//
#include <hip/hip_runtime.h>

// 2-layer GCN, rank-2 factorization + dst-range bucketing + LDS aggregation.
// R6: power-of-2 ranges (rs=4096, shift/mask instead of div), scan fused into
//     k_bcount via last-block pattern, LDS counting-sort bscatter with
//     bucket-major coalesced packed writes.

#define NRMAX 32
#define AGG_BLKS 16
#define CHUNK 4096
#define DBITS 12
#define DMASK 4095

// ---------------- node-local kernels (fused partial merges) ----------------

__global__ void k_px(const float2* __restrict__ x, const int* __restrict__ pdeg,
                     float* __restrict__ dinv, float2* __restrict__ px, int n) {
    int i = blockIdx.x * blockDim.x + threadIdx.x;
    if (i >= n) return;
    int deg = 1;  // self-loop
#pragma unroll
    for (int b = 0; b < AGG_BLKS; ++b) deg += pdeg[b * n + i];
    float d = rsqrtf((float)deg);
    dinv[i] = d;
    float2 xv = x[i];
    px[i] = make_float2(d * xv.x, d * xv.y);
}

__global__ void k_node(const float2* __restrict__ px, const float2* __restrict__ pP,
                       const float* __restrict__ dinv,
                       const float* __restrict__ W1, const float* __restrict__ b1,
                       const float* __restrict__ W2, float* __restrict__ s, int n) {
    int i = blockIdx.x * blockDim.x + threadIdx.x;
    if (i >= n) return;
    float2 v = px[i];
    float ax = v.x, ay = v.y;
#pragma unroll
    for (int b = 0; b < AGG_BLKS; ++b) {
        float2 p = pP[b * n + i];
        ax += p.x; ay += p.y;
    }
    float d = dinv[i];
    float dot = 0.f;
#pragma unroll
    for (int j = 0; j < 32; ++j) {
        float acc = fmaf(ax, W1[j], ay * W1[32 + j]);
        float h = fmaxf(fmaf(d, acc, b1[j]), 0.f);
        dot = fmaf(h, W2[j], dot);
    }
    s[i] = d * dot;
}

__global__ void k_out(const float* __restrict__ s, const float* __restrict__ ps,
                      const float* __restrict__ dinv, const float* __restrict__ b2,
                      float* __restrict__ out, int n) {
    int i = blockIdx.x * blockDim.x + threadIdx.x;
    if (i >= n) return;
    float acc = s[i];  // self-loop
#pragma unroll
    for (int b = 0; b < AGG_BLKS; ++b) acc += ps[b * n + i];
    out[i] = dinv[i] * acc + b2[0];
}

// ---------------- bucketing ----------------

// count per bucket; LAST block performs the exclusive scan (padded to x4)
__global__ void k_bcount(const int* __restrict__ dst, int* __restrict__ btot,
                         int* __restrict__ done, int* __restrict__ bstart,
                         int* __restrict__ bcnt, int* __restrict__ bcur,
                         int e, int NR) {
    __shared__ int h[NRMAX];
    if (threadIdx.x < NRMAX) h[threadIdx.x] = 0;
    __syncthreads();
    int eq = e >> 2;
    const int4* d4 = (const int4*)dst;
    for (int i = blockIdx.x * blockDim.x + threadIdx.x; i < eq; i += gridDim.x * blockDim.x) {
        int4 v = d4[i];
        atomicAdd(&h[v.x >> DBITS], 1);
        atomicAdd(&h[v.y >> DBITS], 1);
        atomicAdd(&h[v.z >> DBITS], 1);
        atomicAdd(&h[v.w >> DBITS], 1);
    }
    if (blockIdx.x == 0 && threadIdx.x == 0)
        for (int i = eq * 4; i < e; ++i) atomicAdd(&h[dst[i] >> DBITS], 1);
    __syncthreads();
    if (threadIdx.x < NR && h[threadIdx.x])
        atomicAdd(&btot[threadIdx.x * 16], h[threadIdx.x]);
    __threadfence();
    __syncthreads();
    if (threadIdx.x == 0) {
        int t = atomicAdd(done, 1);
        if (t == (int)gridDim.x - 1) {   // last block: do the scan
            int acc = 0;
            for (int r = 0; r < NR; ++r) {
                int c = atomicAdd(&btot[r * 16], 0);   // coherent read
                bstart[r] = acc; bcnt[r] = c; bcur[r * 16] = acc;
                acc += (c + 3) & ~3;   // pad starts to x4 (uint4 alignment)
            }
        }
    }
}

// LDS counting-sort per 4096-edge chunk; bucket-major coalesced flush
__global__ void k_bscatter(const int* __restrict__ src, const int* __restrict__ dst,
                           int* __restrict__ bcur, unsigned* __restrict__ packed,
                           int e, int NR) {
    __shared__ int h[NRMAX], lofs[NRMAX], gbase[NRMAX], cur[NRMAX];
    __shared__ unsigned sbuf[CHUNK];   // 16 KB
    int c0 = blockIdx.x * CHUNK;
    int c1 = min(c0 + CHUNK, e);
    if (threadIdx.x < NRMAX) h[threadIdx.x] = 0;
    __syncthreads();
    const int4* d4 = (const int4*)(dst + c0);
    const int4* s4 = (const int4*)(src + c0);
    int len = c1 - c0;
    int lq = len >> 2;
    // pass 1: count
    for (int j = threadIdx.x; j < lq; j += blockDim.x) {
        int4 v = d4[j];
        atomicAdd(&h[v.x >> DBITS], 1);
        atomicAdd(&h[v.y >> DBITS], 1);
        atomicAdd(&h[v.z >> DBITS], 1);
        atomicAdd(&h[v.w >> DBITS], 1);
    }
    if (threadIdx.x == 0)
        for (int i = lq * 4; i < len; ++i) atomicAdd(&h[dst[c0 + i] >> DBITS], 1);
    __syncthreads();
    // local prefix
    if (threadIdx.x == 0) {
        int acc = 0;
        for (int r = 0; r < NR; ++r) { lofs[r] = acc; acc += h[r]; }
    }
    __syncthreads();
    // reserve global ranges; init local cursors
    if (threadIdx.x < NR) {
        cur[threadIdx.x] = lofs[threadIdx.x];
        if (h[threadIdx.x] > 0)
            gbase[threadIdx.x] = atomicAdd(&bcur[threadIdx.x * 16], h[threadIdx.x]);
    }
    __syncthreads();
    // pass 2: place into LDS sorted by bucket
    for (int j = threadIdx.x; j < lq; j += blockDim.x) {
        int4 dv = d4[j];
        int4 sv = s4[j];
        int r0 = dv.x >> DBITS; int t0 = atomicAdd(&cur[r0], 1);
        sbuf[t0] = ((unsigned)sv.x << DBITS) | (unsigned)(dv.x & DMASK);
        int r1 = dv.y >> DBITS; int t1 = atomicAdd(&cur[r1], 1);
        sbuf[t1] = ((unsigned)sv.y << DBITS) | (unsigned)(dv.y & DMASK);
        int r2 = dv.z >> DBITS; int t2 = atomicAdd(&cur[r2], 1);
        sbuf[t2] = ((unsigned)sv.z << DBITS) | (unsigned)(dv.z & DMASK);
        int r3 = dv.w >> DBITS; int t3 = atomicAdd(&cur[r3], 1);
        sbuf[t3] = ((unsigned)sv.w << DBITS) | (unsigned)(dv.w & DMASK);
    }
    if (threadIdx.x == 0)
        for (int i = lq * 4; i < len; ++i) {
            int d = dst[c0 + i];
            int r = d >> DBITS;
            int t = atomicAdd(&cur[r], 1);
            sbuf[t] = ((unsigned)src[c0 + i] << DBITS) | (unsigned)(d & DMASK);
        }
    __syncthreads();
    // pass 3: bucket-major coalesced copy-out
    for (int r = 0; r < NR; ++r) {
        int cnt = h[r], lo = lofs[r], gb = gbase[r];
        for (int t = threadIdx.x; t < cnt; t += blockDim.x)
            packed[gb + t] = sbuf[lo + t];
    }
}

// ---------------- LDS aggregations -> partials (no global atomics) ----------

__global__ __launch_bounds__(1024, 8)
void k_deg(const unsigned* __restrict__ packed, const int* __restrict__ bstart,
           const int* __restrict__ bcnt, int* __restrict__ pdeg, int n) {
    __shared__ int acc[DMASK + 1];   // 16 KB
    int r = blockIdx.y, b = blockIdx.x;
    int rs_r = min(DMASK + 1, n - (r << DBITS));
    for (int t = threadIdx.x; t < rs_r; t += blockDim.x) acc[t] = 0;
    __syncthreads();
    int c = bcnt[r], base = bstart[r];
    int q = (c + 3) >> 2;
    int qper = (q + gridDim.x - 1) / gridDim.x;
    int qlo = b * qper, qhi = min(qlo + qper, q);
    const uint4* p4 = (const uint4*)(packed + base);
    for (int j = qlo + threadIdx.x; j < qhi; j += blockDim.x) {
        uint4 v = p4[j];
        int lim = c - j * 4;
        atomicAdd(&acc[v.x & DMASK], 1);
        if (lim > 1) atomicAdd(&acc[v.y & DMASK], 1);
        if (lim > 2) atomicAdd(&acc[v.z & DMASK], 1);
        if (lim > 3) atomicAdd(&acc[v.w & DMASK], 1);
    }
    __syncthreads();
    int nb = b * n + (r << DBITS);
    for (int t = threadIdx.x; t < rs_r; t += blockDim.x) pdeg[nb + t] = acc[t];
}

__global__ __launch_bounds__(1024, 8)
void k_agg1(const unsigned* __restrict__ packed, const int* __restrict__ bstart,
            const int* __restrict__ bcnt, const float2* __restrict__ px,
            float2* __restrict__ pP, int n) {
    __shared__ float acc[2 * (DMASK + 1)];   // 32 KB
    int r = blockIdx.y, b = blockIdx.x;
    int rs_r = min(DMASK + 1, n - (r << DBITS));
    for (int t = threadIdx.x; t < 2 * rs_r; t += blockDim.x) acc[t] = 0.f;
    __syncthreads();
    int c = bcnt[r], base = bstart[r];
    int q = (c + 3) >> 2;
    int qper = (q + gridDim.x - 1) / gridDim.x;
    int qlo = b * qper, qhi = min(qlo + qper, q);
    const uint4* p4 = (const uint4*)(packed + base);
    int nm1 = n - 1;
    for (int j = qlo + threadIdx.x; j < qhi; j += blockDim.x) {
        uint4 v = p4[j];
        int i0 = (int)(v.x >> DBITS);                // quad has >=1 valid elem
        int i1 = min((int)(v.y >> DBITS), nm1);      // pad lanes: clamp index
        int i2 = min((int)(v.z >> DBITS), nm1);
        int i3 = min((int)(v.w >> DBITS), nm1);
        float2 g0 = px[i0], g1 = px[i1], g2 = px[i2], g3 = px[i3];
        int lim = c - j * 4;
        int d0 = (v.x & DMASK) * 2;
        atomicAdd(&acc[d0], g0.x); atomicAdd(&acc[d0 + 1], g0.y);
        if (lim > 1) { int d1 = (v.y & DMASK) * 2; atomicAdd(&acc[d1], g1.x); atomicAdd(&acc[d1 + 1], g1.y); }
        if (lim > 2) { int d2 = (v.z & DMASK) * 2; atomicAdd(&acc[d2], g2.x); atomicAdd(&acc[d2 + 1], g2.y); }
        if (lim > 3) { int d3 = (v.w & DMASK) * 2; atomicAdd(&acc[d3], g3.x); atomicAdd(&acc[d3 + 1], g3.y); }
    }
    __syncthreads();
    int nb = b * n + (r << DBITS);
    for (int t = threadIdx.x; t < rs_r; t += blockDim.x)
        pP[nb + t] = make_float2(acc[2 * t], acc[2 * t + 1]);
}

__global__ __launch_bounds__(1024, 8)
void k_agg2(const unsigned* __restrict__ packed, const int* __restrict__ bstart,
            const int* __restrict__ bcnt, const float* __restrict__ s,
            float* __restrict__ ps, int n) {
    __shared__ float acc[DMASK + 1];   // 16 KB
    int r = blockIdx.y, b = blockIdx.x;
    int rs_r = min(DMASK + 1, n - (r << DBITS));
    for (int t = threadIdx.x; t < rs_r; t += blockDim.x) acc[t] = 0.f;
    __syncthreads();
    int c = bcnt[r], base = bstart[r];
    int q = (c + 3) >> 2;
    int qper = (q + gridDim.x - 1) / gridDim.x;
    int qlo = b * qper, qhi = min(qlo + qper, q);
    const uint4* p4 = (const uint4*)(packed + base);
    int nm1 = n - 1;
    for (int j = qlo + threadIdx.x; j < qhi; j += blockDim.x) {
        uint4 v = p4[j];
        int i0 = (int)(v.x >> DBITS);
        int i1 = min((int)(v.y >> DBITS), nm1);
        int i2 = min((int)(v.z >> DBITS), nm1);
        int i3 = min((int)(v.w >> DBITS), nm1);
        float g0 = s[i0], g1 = s[i1], g2 = s[i2], g3 = s[i3];
        int lim = c - j * 4;
        atomicAdd(&acc[v.x & DMASK], g0);
        if (lim > 1) atomicAdd(&acc[v.y & DMASK], g1);
        if (lim > 2) atomicAdd(&acc[v.z & DMASK], g2);
        if (lim > 3) atomicAdd(&acc[v.w & DMASK], g3);
    }
    __syncthreads();
    int nb = b * n + (r << DBITS);
    for (int t = threadIdx.x; t < rs_r; t += blockDim.x) ps[nb + t] = acc[t];
}

// ---------------- fallback path (round-2 style) ----------------

__global__ void f_zero(int* __restrict__ ideg, float2* __restrict__ P, int n) {
    int i = blockIdx.x * blockDim.x + threadIdx.x;
    if (i < n) { ideg[i] = 0; P[i] = make_float2(0.f, 0.f); }
}
__global__ void f_count(const int* __restrict__ dst, int* __restrict__ ideg, int e) {
    int i = blockIdx.x * blockDim.x + threadIdx.x;
    if (i < e) atomicAdd(&ideg[dst[i]], 1);
}
__global__ void f_px(const float2* __restrict__ x, const int* __restrict__ ideg,
                     float* __restrict__ dinv, float2* __restrict__ px, int n) {
    int i = blockIdx.x * blockDim.x + threadIdx.x;
    if (i >= n) return;
    float d = rsqrtf((float)(1 + ideg[i]));
    dinv[i] = d;
    float2 xv = x[i];
    px[i] = make_float2(d * xv.x, d * xv.y);
}
__global__ void f_scatter_px(const int* __restrict__ src, const int* __restrict__ dst,
                             const float2* __restrict__ px, float* __restrict__ Pf, int e) {
    int i = blockIdx.x * blockDim.x + threadIdx.x;
    if (i >= e) return;
    int sidx = src[i], d = dst[i];
    float2 v = px[sidx];
    atomicAdd(&Pf[2 * d], v.x);
    atomicAdd(&Pf[2 * d + 1], v.y);
}
__global__ void f_node(const float2* __restrict__ px, const float2* __restrict__ P,
                       const float* __restrict__ dinv,
                       const float* __restrict__ W1, const float* __restrict__ b1,
                       const float* __restrict__ W2,
                       float* __restrict__ s, float* __restrict__ S, int n) {
    int i = blockIdx.x * blockDim.x + threadIdx.x;
    if (i >= n) return;
    float d = dinv[i];
    float2 v = px[i], p = P[i];
    float ax = v.x + p.x, ay = v.y + p.y;
    float dot = 0.f;
#pragma unroll
    for (int j = 0; j < 32; ++j) {
        float acc = fmaf(ax, W1[j], ay * W1[32 + j]);
        float h = fmaxf(fmaf(d, acc, b1[j]), 0.f);
        dot = fmaf(h, W2[j], dot);
    }
    float sv = d * dot;
    s[i] = sv;
    S[i] = sv;
}
__global__ void f_scatter_s(const int* __restrict__ src, const int* __restrict__ dst,
                            const float* __restrict__ s, float* __restrict__ S, int e) {
    int i = blockIdx.x * blockDim.x + threadIdx.x;
    if (i < e) atomicAdd(&S[dst[i]], s[src[i]]);
}
__global__ void f_out(const float* __restrict__ S, const float* __restrict__ dinv,
                      const float* __restrict__ b2, float* __restrict__ out, int n) {
    int i = blockIdx.x * blockDim.x + threadIdx.x;
    if (i < n) out[i] = dinv[i] * S[i] + b2[0];
}

// ---------------- launch ----------------

extern "C" void kernel_launch(void* const* d_in, const int* in_sizes, int n_in,
                              void* d_out, int out_size, void* d_ws, size_t ws_size,
                              hipStream_t stream) {
    const float* x  = (const float*)d_in[0];
    const int*   ei = (const int*)d_in[1];
    const float* W1 = (const float*)d_in[2];
    const float* b1 = (const float*)d_in[3];
    const float* W2 = (const float*)d_in[4];
    const float* b2 = (const float*)d_in[5];
    float* out = (float*)d_out;

    int n = in_sizes[0] / 2;   // 100000
    int e = in_sizes[1] / 2;   // 2560000
    const int* src = ei;
    const int* dst = ei + e;
    int NR = (n + DMASK) >> DBITS;   // 25 ranges of 4096

    char* ws = (char*)d_ws;
    auto align = [](size_t v) { return (v + 255) & ~(size_t)255; };
    size_t off = 0;
    float*  dinv = (float*) (ws + off); off = align(off + (size_t)n * 4);
    float2* px   = (float2*)(ws + off); off = align(off + (size_t)n * 8);
    float*  s    = (float*) (ws + off); off = align(off + (size_t)n * 4);
    int*    pdeg = (int*)   (ws + off); off = align(off + (size_t)AGG_BLKS * n * 4);
    float2* pP   = (float2*)(ws + off); off = align(off + (size_t)AGG_BLKS * n * 8);
    float*  ps   = (float*) (ws + off); off = align(off + (size_t)AGG_BLKS * n * 4);
    int*    bstart = (int*)(ws + off); off = align(off + NRMAX * 4);
    int*    bcnt   = (int*)(ws + off); off = align(off + NRMAX * 4);
    // contiguous control block (zeroed each call): btot | bcur | done
    int*    btot   = (int*)(ws + off);
    int*    bcur   = btot + NRMAX * 16;
    int*    done   = bcur + NRMAX * 16;
    size_t  ctrl_bytes = (size_t)(NRMAX * 16 * 2 + 16) * 4;
    off = align(off + ctrl_bytes);
    unsigned* packed = (unsigned*)(ws + off);
    size_t need = off + (size_t)(e + 4 * NRMAX) * 4;

    const int B = 256;
    int gn = (n + B - 1) / B, ge = (e + B - 1) / B;

    bool fast = (need <= ws_size) && (NR <= NRMAX) && (n <= (1 << 17));

    if (fast) {
        dim3 ag(AGG_BLKS, NR);
        hipMemsetAsync(btot, 0, ctrl_bytes, stream);
        k_bcount  <<<512, B, 0, stream>>>(dst, btot, done, bstart, bcnt, bcur, e, NR);
        k_bscatter<<<(e + CHUNK - 1) / CHUNK, B, 0, stream>>>(src, dst, bcur, packed, e, NR);
        k_deg     <<<ag, 1024, 0, stream>>>(packed, bstart, bcnt, pdeg, n);
        k_px      <<<gn, B, 0, stream>>>((const float2*)x, pdeg, dinv, px, n);
        k_agg1    <<<ag, 1024, 0, stream>>>(packed, bstart, bcnt, px, pP, n);
        k_node    <<<gn, B, 0, stream>>>(px, pP, dinv, W1, b1, W2, s, n);
        k_agg2    <<<ag, 1024, 0, stream>>>(packed, bstart, bcnt, s, ps, n);
        k_out     <<<gn, B, 0, stream>>>(s, ps, dinv, b2, out, n);
    } else {
        int*   ideg = pdeg;
        float2* P   = pP;
        float* S    = ps;
        f_zero      <<<gn, B, 0, stream>>>(ideg, P, n);
        f_count     <<<ge, B, 0, stream>>>(dst, ideg, e);
        f_px        <<<gn, B, 0, stream>>>((const float2*)x, ideg, dinv, px, n);
        f_scatter_px<<<ge, B, 0, stream>>>(src, dst, px, (float*)P, e);
        f_node      <<<gn, B, 0, stream>>>(px, P, dinv, W1, b1, W2, s, S, n);
        f_scatter_s <<<ge, B, 0, stream>>>(src, dst, s, S, e);
        f_out       <<<gn, B, 0, stream>>>(S, dinv, b2, out, n);
    }
}

// Round 7
// 117.556 us; speedup vs baseline: 1.2556x; 1.2556x over previous
//
#include <hip/hip_runtime.h>

// 2-layer GCN, rank-2 factorization + dst-range bucketing + LDS aggregation.
// R7: ZERO cross-block global atomics. count -> wave-scan -> LDS-sort scatter
//     with precomputed per-chunk bucket offsets (the contended same-line
//     atomic RMW chains in bcount/bscatter were ~80ns/op serialized = the
//     45us floor seen in R6's k_bcount).

#define NRMAX 32
#define AGG_BLKS 16
#define CHUNK 4096
#define NCHMAX 1024      // max chunks supported by k_scan (e <= 4M edges)
#define DBITS 12
#define DMASK 4095

// ---------------- node-local kernels (fused partial merges) ----------------

__global__ void k_px(const float2* __restrict__ x, const int* __restrict__ pdeg,
                     float* __restrict__ dinv, float2* __restrict__ px, int n) {
    int i = blockIdx.x * blockDim.x + threadIdx.x;
    if (i >= n) return;
    int deg = 1;  // self-loop
#pragma unroll
    for (int b = 0; b < AGG_BLKS; ++b) deg += pdeg[b * n + i];
    float d = rsqrtf((float)deg);
    dinv[i] = d;
    float2 xv = x[i];
    px[i] = make_float2(d * xv.x, d * xv.y);
}

__global__ void k_node(const float2* __restrict__ px, const float2* __restrict__ pP,
                       const float* __restrict__ dinv,
                       const float* __restrict__ W1, const float* __restrict__ b1,
                       const float* __restrict__ W2, float* __restrict__ s, int n) {
    int i = blockIdx.x * blockDim.x + threadIdx.x;
    if (i >= n) return;
    float2 v = px[i];
    float ax = v.x, ay = v.y;
#pragma unroll
    for (int b = 0; b < AGG_BLKS; ++b) {
        float2 p = pP[b * n + i];
        ax += p.x; ay += p.y;
    }
    float d = dinv[i];
    float dot = 0.f;
#pragma unroll
    for (int j = 0; j < 32; ++j) {
        float acc = fmaf(ax, W1[j], ay * W1[32 + j]);
        float h = fmaxf(fmaf(d, acc, b1[j]), 0.f);
        dot = fmaf(h, W2[j], dot);
    }
    s[i] = d * dot;
}

__global__ void k_out(const float* __restrict__ s, const float* __restrict__ ps,
                      const float* __restrict__ dinv, const float* __restrict__ b2,
                      float* __restrict__ out, int n) {
    int i = blockIdx.x * blockDim.x + threadIdx.x;
    if (i >= n) return;
    float acc = s[i];  // self-loop
#pragma unroll
    for (int b = 0; b < AGG_BLKS; ++b) acc += ps[b * n + i];
    out[i] = dinv[i] * acc + b2[0];
}

// ---------------- bucketing: count -> scan -> scatter (atomic-free) --------

// per-chunk LDS histogram -> plain stores cnt[r*NCHMAX + chunk]
__global__ void k_cnt(const int* __restrict__ dst, int* __restrict__ cnt,
                      int e, int NR) {
    __shared__ int h[NRMAX];
    if (threadIdx.x < NRMAX) h[threadIdx.x] = 0;
    __syncthreads();
    int c0 = blockIdx.x * CHUNK;
    int c1 = min(c0 + CHUNK, e);
    int len = c1 - c0, lq = len >> 2;
    const int4* d4 = (const int4*)(dst + c0);
    for (int j = threadIdx.x; j < lq; j += blockDim.x) {
        int4 v = d4[j];
        atomicAdd(&h[v.x >> DBITS], 1);
        atomicAdd(&h[v.y >> DBITS], 1);
        atomicAdd(&h[v.z >> DBITS], 1);
        atomicAdd(&h[v.w >> DBITS], 1);
    }
    if (threadIdx.x == 0)
        for (int i = lq * 4; i < len; ++i) atomicAdd(&h[dst[c0 + i] >> DBITS], 1);
    __syncthreads();
    if (threadIdx.x < NR) cnt[(threadIdx.x << 10) + blockIdx.x] = h[threadIdx.x];
}

// one block: per-bucket exclusive scan over chunks (wave-parallel shuffle scan),
// then bucket-base scan (x4-padded starts), add bases into ofs.
__global__ __launch_bounds__(1024)
void k_scan(const int* __restrict__ cnt, int* __restrict__ ofs,
            int* __restrict__ bstart, int* __restrict__ bcnt, int NR, int NCH) {
    __shared__ int tot[NRMAX], bs[NRMAX];
    int tid = threadIdx.x, lane = tid & 63, wid = tid >> 6;
    for (int r = wid; r < NR; r += 16) {
        int base = 0;
        for (int c0 = 0; c0 < NCH; c0 += 64) {
            int c = c0 + lane;
            int orig = (c < NCH) ? cnt[(r << 10) + c] : 0;
            int v = orig;
#pragma unroll
            for (int d = 1; d < 64; d <<= 1) {
                int u = __shfl_up(v, d);
                if (lane >= d) v += u;
            }
            if (c < NCH) ofs[(r << 10) + c] = base + v - orig;  // exclusive
            base += __shfl(v, 63);
        }
        tot[r] = base;
    }
    __syncthreads();
    if (tid == 0) {
        int acc = 0;
        for (int r = 0; r < NR; ++r) {
            bs[r] = acc; bstart[r] = acc; bcnt[r] = tot[r];
            acc += (tot[r] + 3) & ~3;   // pad bucket starts to x4 (uint4)
        }
    }
    __syncthreads();
    for (int i = tid; i < (NR << 10); i += 1024) {
        int c = i & (NCHMAX - 1);
        if (c < NCH) ofs[i] += bs[i >> 10];
    }
}

// LDS counting-sort per chunk; bucket-major coalesced flush to exact offsets
__global__ void k_bscatter(const int* __restrict__ src, const int* __restrict__ dst,
                           const int* __restrict__ ofs, unsigned* __restrict__ packed,
                           int e, int NR) {
    __shared__ int h[NRMAX], lofs[NRMAX], cur[NRMAX], gbase[NRMAX];
    __shared__ unsigned sbuf[CHUNK];   // 16 KB
    int blk = blockIdx.x;
    int c0 = blk * CHUNK;
    int c1 = min(c0 + CHUNK, e);
    int len = c1 - c0, lq = len >> 2;
    if (threadIdx.x < NRMAX) h[threadIdx.x] = 0;
    __syncthreads();
    const int4* d4 = (const int4*)(dst + c0);
    const int4* s4 = (const int4*)(src + c0);
    // pass 1: count
    for (int j = threadIdx.x; j < lq; j += blockDim.x) {
        int4 v = d4[j];
        atomicAdd(&h[v.x >> DBITS], 1);
        atomicAdd(&h[v.y >> DBITS], 1);
        atomicAdd(&h[v.z >> DBITS], 1);
        atomicAdd(&h[v.w >> DBITS], 1);
    }
    if (threadIdx.x == 0)
        for (int i = lq * 4; i < len; ++i) atomicAdd(&h[dst[c0 + i] >> DBITS], 1);
    __syncthreads();
    // local prefix
    if (threadIdx.x == 0) {
        int acc = 0;
        for (int r = 0; r < NR; ++r) { lofs[r] = acc; acc += h[r]; }
    }
    __syncthreads();
    if (threadIdx.x < NR) {
        cur[threadIdx.x]   = lofs[threadIdx.x];
        gbase[threadIdx.x] = ofs[(threadIdx.x << 10) + blk];  // precomputed, no atomics
    }
    __syncthreads();
    // pass 2: place into LDS sorted by bucket
    for (int j = threadIdx.x; j < lq; j += blockDim.x) {
        int4 dv = d4[j];
        int4 sv = s4[j];
        int r0 = dv.x >> DBITS; int t0 = atomicAdd(&cur[r0], 1);
        sbuf[t0] = ((unsigned)sv.x << DBITS) | (unsigned)(dv.x & DMASK);
        int r1 = dv.y >> DBITS; int t1 = atomicAdd(&cur[r1], 1);
        sbuf[t1] = ((unsigned)sv.y << DBITS) | (unsigned)(dv.y & DMASK);
        int r2 = dv.z >> DBITS; int t2 = atomicAdd(&cur[r2], 1);
        sbuf[t2] = ((unsigned)sv.z << DBITS) | (unsigned)(dv.z & DMASK);
        int r3 = dv.w >> DBITS; int t3 = atomicAdd(&cur[r3], 1);
        sbuf[t3] = ((unsigned)sv.w << DBITS) | (unsigned)(dv.w & DMASK);
    }
    if (threadIdx.x == 0)
        for (int i = lq * 4; i < len; ++i) {
            int d = dst[c0 + i];
            int r = d >> DBITS;
            int t = atomicAdd(&cur[r], 1);
            sbuf[t] = ((unsigned)src[c0 + i] << DBITS) | (unsigned)(d & DMASK);
        }
    __syncthreads();
    // pass 3: bucket-major coalesced copy-out
    for (int r = 0; r < NR; ++r) {
        int c = h[r], lo = lofs[r], gb = gbase[r];
        for (int t = threadIdx.x; t < c; t += blockDim.x)
            packed[gb + t] = sbuf[lo + t];
    }
}

// ---------------- LDS aggregations -> partials (no global atomics) ----------

__global__ __launch_bounds__(1024, 8)
void k_deg(const unsigned* __restrict__ packed, const int* __restrict__ bstart,
           const int* __restrict__ bcnt, int* __restrict__ pdeg, int n) {
    __shared__ int acc[DMASK + 1];   // 16 KB
    int r = blockIdx.y, b = blockIdx.x;
    int rs_r = min(DMASK + 1, n - (r << DBITS));
    for (int t = threadIdx.x; t < rs_r; t += blockDim.x) acc[t] = 0;
    __syncthreads();
    int c = bcnt[r], base = bstart[r];
    int q = (c + 3) >> 2;
    int qper = (q + AGG_BLKS - 1) / AGG_BLKS;
    int qlo = b * qper, qhi = min(qlo + qper, q);
    const uint4* p4 = (const uint4*)(packed + base);
    for (int j = qlo + threadIdx.x; j < qhi; j += blockDim.x) {
        uint4 v = p4[j];
        int lim = c - j * 4;
        atomicAdd(&acc[v.x & DMASK], 1);
        if (lim > 1) atomicAdd(&acc[v.y & DMASK], 1);
        if (lim > 2) atomicAdd(&acc[v.z & DMASK], 1);
        if (lim > 3) atomicAdd(&acc[v.w & DMASK], 1);
    }
    __syncthreads();
    int nb = b * n + (r << DBITS);
    for (int t = threadIdx.x; t < rs_r; t += blockDim.x) pdeg[nb + t] = acc[t];
}

__global__ __launch_bounds__(1024, 8)
void k_agg1(const unsigned* __restrict__ packed, const int* __restrict__ bstart,
            const int* __restrict__ bcnt, const float2* __restrict__ px,
            float2* __restrict__ pP, int n) {
    __shared__ float acc[2 * (DMASK + 1)];   // 32 KB
    int r = blockIdx.y, b = blockIdx.x;
    int rs_r = min(DMASK + 1, n - (r << DBITS));
    for (int t = threadIdx.x; t < 2 * rs_r; t += blockDim.x) acc[t] = 0.f;
    __syncthreads();
    int c = bcnt[r], base = bstart[r];
    int q = (c + 3) >> 2;
    int qper = (q + AGG_BLKS - 1) / AGG_BLKS;
    int qlo = b * qper, qhi = min(qlo + qper, q);
    const uint4* p4 = (const uint4*)(packed + base);
    int nm1 = n - 1;
    for (int j = qlo + threadIdx.x; j < qhi; j += blockDim.x) {
        uint4 v = p4[j];
        int i0 = (int)(v.x >> DBITS);                // quad has >=1 valid elem
        int i1 = min((int)(v.y >> DBITS), nm1);      // pad lanes: clamp index
        int i2 = min((int)(v.z >> DBITS), nm1);
        int i3 = min((int)(v.w >> DBITS), nm1);
        float2 g0 = px[i0], g1 = px[i1], g2 = px[i2], g3 = px[i3];
        int lim = c - j * 4;
        int d0 = (v.x & DMASK) * 2;
        atomicAdd(&acc[d0], g0.x); atomicAdd(&acc[d0 + 1], g0.y);
        if (lim > 1) { int d1 = (v.y & DMASK) * 2; atomicAdd(&acc[d1], g1.x); atomicAdd(&acc[d1 + 1], g1.y); }
        if (lim > 2) { int d2 = (v.z & DMASK) * 2; atomicAdd(&acc[d2], g2.x); atomicAdd(&acc[d2 + 1], g2.y); }
        if (lim > 3) { int d3 = (v.w & DMASK) * 2; atomicAdd(&acc[d3], g3.x); atomicAdd(&acc[d3 + 1], g3.y); }
    }
    __syncthreads();
    int nb = b * n + (r << DBITS);
    for (int t = threadIdx.x; t < rs_r; t += blockDim.x)
        pP[nb + t] = make_float2(acc[2 * t], acc[2 * t + 1]);
}

__global__ __launch_bounds__(1024, 8)
void k_agg2(const unsigned* __restrict__ packed, const int* __restrict__ bstart,
            const int* __restrict__ bcnt, const float* __restrict__ s,
            float* __restrict__ ps, int n) {
    __shared__ float acc[DMASK + 1];   // 16 KB
    int r = blockIdx.y, b = blockIdx.x;
    int rs_r = min(DMASK + 1, n - (r << DBITS));
    for (int t = threadIdx.x; t < rs_r; t += blockDim.x) acc[t] = 0.f;
    __syncthreads();
    int c = bcnt[r], base = bstart[r];
    int q = (c + 3) >> 2;
    int qper = (q + AGG_BLKS - 1) / AGG_BLKS;
    int qlo = b * qper, qhi = min(qlo + qper, q);
    const uint4* p4 = (const uint4*)(packed + base);
    int nm1 = n - 1;
    for (int j = qlo + threadIdx.x; j < qhi; j += blockDim.x) {
        uint4 v = p4[j];
        int i0 = (int)(v.x >> DBITS);
        int i1 = min((int)(v.y >> DBITS), nm1);
        int i2 = min((int)(v.z >> DBITS), nm1);
        int i3 = min((int)(v.w >> DBITS), nm1);
        float g0 = s[i0], g1 = s[i1], g2 = s[i2], g3 = s[i3];
        int lim = c - j * 4;
        atomicAdd(&acc[v.x & DMASK], g0);
        if (lim > 1) atomicAdd(&acc[v.y & DMASK], g1);
        if (lim > 2) atomicAdd(&acc[v.z & DMASK], g2);
        if (lim > 3) atomicAdd(&acc[v.w & DMASK], g3);
    }
    __syncthreads();
    int nb = b * n + (r << DBITS);
    for (int t = threadIdx.x; t < rs_r; t += blockDim.x) ps[nb + t] = acc[t];
}

// ---------------- fallback path (round-2 style) ----------------

__global__ void f_zero(int* __restrict__ ideg, float2* __restrict__ P, int n) {
    int i = blockIdx.x * blockDim.x + threadIdx.x;
    if (i < n) { ideg[i] = 0; P[i] = make_float2(0.f, 0.f); }
}
__global__ void f_count(const int* __restrict__ dst, int* __restrict__ ideg, int e) {
    int i = blockIdx.x * blockDim.x + threadIdx.x;
    if (i < e) atomicAdd(&ideg[dst[i]], 1);
}
__global__ void f_px(const float2* __restrict__ x, const int* __restrict__ ideg,
                     float* __restrict__ dinv, float2* __restrict__ px, int n) {
    int i = blockIdx.x * blockDim.x + threadIdx.x;
    if (i >= n) return;
    float d = rsqrtf((float)(1 + ideg[i]));
    dinv[i] = d;
    float2 xv = x[i];
    px[i] = make_float2(d * xv.x, d * xv.y);
}
__global__ void f_scatter_px(const int* __restrict__ src, const int* __restrict__ dst,
                             const float2* __restrict__ px, float* __restrict__ Pf, int e) {
    int i = blockIdx.x * blockDim.x + threadIdx.x;
    if (i >= e) return;
    int sidx = src[i], d = dst[i];
    float2 v = px[sidx];
    atomicAdd(&Pf[2 * d], v.x);
    atomicAdd(&Pf[2 * d + 1], v.y);
}
__global__ void f_node(const float2* __restrict__ px, const float2* __restrict__ P,
                       const float* __restrict__ dinv,
                       const float* __restrict__ W1, const float* __restrict__ b1,
                       const float* __restrict__ W2,
                       float* __restrict__ s, float* __restrict__ S, int n) {
    int i = blockIdx.x * blockDim.x + threadIdx.x;
    if (i >= n) return;
    float d = dinv[i];
    float2 v = px[i], p = P[i];
    float ax = v.x + p.x, ay = v.y + p.y;
    float dot = 0.f;
#pragma unroll
    for (int j = 0; j < 32; ++j) {
        float acc = fmaf(ax, W1[j], ay * W1[32 + j]);
        float h = fmaxf(fmaf(d, acc, b1[j]), 0.f);
        dot = fmaf(h, W2[j], dot);
    }
    float sv = d * dot;
    s[i] = sv;
    S[i] = sv;
}
__global__ void f_scatter_s(const int* __restrict__ src, const int* __restrict__ dst,
                            const float* __restrict__ s, float* __restrict__ S, int e) {
    int i = blockIdx.x * blockDim.x + threadIdx.x;
    if (i < e) atomicAdd(&S[dst[i]], s[src[i]]);
}
__global__ void f_out(const float* __restrict__ S, const float* __restrict__ dinv,
                      const float* __restrict__ b2, float* __restrict__ out, int n) {
    int i = blockIdx.x * blockDim.x + threadIdx.x;
    if (i < n) out[i] = dinv[i] * S[i] + b2[0];
}

// ---------------- launch ----------------

extern "C" void kernel_launch(void* const* d_in, const int* in_sizes, int n_in,
                              void* d_out, int out_size, void* d_ws, size_t ws_size,
                              hipStream_t stream) {
    const float* x  = (const float*)d_in[0];
    const int*   ei = (const int*)d_in[1];
    const float* W1 = (const float*)d_in[2];
    const float* b1 = (const float*)d_in[3];
    const float* W2 = (const float*)d_in[4];
    const float* b2 = (const float*)d_in[5];
    float* out = (float*)d_out;

    int n = in_sizes[0] / 2;   // 100000
    int e = in_sizes[1] / 2;   // 2560000
    const int* src = ei;
    const int* dst = ei + e;
    int NR  = (n + DMASK) >> DBITS;          // 25 ranges of 4096
    int NCH = (e + CHUNK - 1) / CHUNK;       // 625 chunks

    char* ws = (char*)d_ws;
    auto align = [](size_t v) { return (v + 255) & ~(size_t)255; };
    size_t off = 0;
    float*  dinv = (float*) (ws + off); off = align(off + (size_t)n * 4);
    float2* px   = (float2*)(ws + off); off = align(off + (size_t)n * 8);
    float*  s    = (float*) (ws + off); off = align(off + (size_t)n * 4);
    int*    pdeg = (int*)   (ws + off); off = align(off + (size_t)AGG_BLKS * n * 4);
    float2* pP   = (float2*)(ws + off); off = align(off + (size_t)AGG_BLKS * n * 8);
    float*  ps   = (float*) (ws + off); off = align(off + (size_t)AGG_BLKS * n * 4);
    int*    bstart = (int*)(ws + off); off = align(off + NRMAX * 4);
    int*    bcnt   = (int*)(ws + off); off = align(off + NRMAX * 4);
    int*    cnt    = (int*)(ws + off); off = align(off + (size_t)NRMAX * NCHMAX * 4);
    int*    ofs    = (int*)(ws + off); off = align(off + (size_t)NRMAX * NCHMAX * 4);
    unsigned* packed = (unsigned*)(ws + off);
    size_t need = off + (size_t)(e + 4 * NRMAX) * 4;

    const int B = 256;
    int gn = (n + B - 1) / B, ge = (e + B - 1) / B;

    bool fast = (need <= ws_size) && (NR <= NRMAX) && (NCH <= NCHMAX) && (n <= (1 << 17));

    if (fast) {
        dim3 ag(AGG_BLKS, NR);
        k_cnt     <<<NCH, B, 0, stream>>>(dst, cnt, e, NR);
        k_scan    <<<1, 1024, 0, stream>>>(cnt, ofs, bstart, bcnt, NR, NCH);
        k_bscatter<<<NCH, B, 0, stream>>>(src, dst, ofs, packed, e, NR);
        k_deg     <<<ag, 1024, 0, stream>>>(packed, bstart, bcnt, pdeg, n);
        k_px      <<<gn, B, 0, stream>>>((const float2*)x, pdeg, dinv, px, n);
        k_agg1    <<<ag, 1024, 0, stream>>>(packed, bstart, bcnt, px, pP, n);
        k_node    <<<gn, B, 0, stream>>>(px, pP, dinv, W1, b1, W2, s, n);
        k_agg2    <<<ag, 1024, 0, stream>>>(packed, bstart, bcnt, s, ps, n);
        k_out     <<<gn, B, 0, stream>>>(s, ps, dinv, b2, out, n);
    } else {
        int*   ideg = pdeg;
        float2* P   = pP;
        float* S    = ps;
        f_zero      <<<gn, B, 0, stream>>>(ideg, P, n);
        f_count     <<<ge, B, 0, stream>>>(dst, ideg, e);
        f_px        <<<gn, B, 0, stream>>>((const float2*)x, ideg, dinv, px, n);
        f_scatter_px<<<ge, B, 0, stream>>>(src, dst, px, (float*)P, e);
        f_node      <<<gn, B, 0, stream>>>(px, P, dinv, W1, b1, W2, s, S, n);
        f_scatter_s <<<ge, B, 0, stream>>>(src, dst, s, S, e);
        f_out       <<<gn, B, 0, stream>>>(S, dinv, b2, out, n);
    }
}